// Round 5
// baseline (86.685 us; speedup 1.0000x reference)
//
#include <hip/hip_runtime.h>
#include <hip/hip_bf16.h>

#define B_ 8
#define H_ 8
#define S_ 1024
#define D_ 64
#define QT 128  // q rows per block (32 per wave)
#define KT 64   // k cols per tile
#define NT (S_ / KT)

typedef float f32x16 __attribute__((ext_vector_type(16)));
typedef float f32x8v __attribute__((ext_vector_type(8)));
typedef float f32x4v __attribute__((ext_vector_type(4)));
typedef short s16x8 __attribute__((ext_vector_type(8)));
typedef unsigned int u32;

// (1/sqrt(2*D)) * log2(e): softmax done base-2; folded into Q at load time
#define CSCALE ((float)(1.4426950408889634 / 11.313708498984761))

static __device__ __forceinline__ unsigned short f2bf(float f) {
    union { float f; unsigned u; } v; v.f = f;
    unsigned r = v.u + 0x7FFF + ((v.u >> 16) & 1);   // RNE
    return (unsigned short)(r >> 16);
}

static __device__ __forceinline__ u32 cvtpk(float lo, float hi) {
    u32 r;
    asm("v_cvt_pk_bf16_f32 %0, %1, %2" : "=v"(r) : "v"(lo), "v"(hi));
    return r;
}

static __device__ __forceinline__ float vmax16(const f32x16 v) {
    f32x8v a = __builtin_shufflevector(v, v, 0, 1, 2, 3, 4, 5, 6, 7);
    f32x8v b = __builtin_shufflevector(v, v, 8, 9, 10, 11, 12, 13, 14, 15);
    f32x8v m8 = __builtin_elementwise_max(a, b);
    f32x4v c = __builtin_shufflevector(m8, m8, 0, 1, 2, 3);
    f32x4v d = __builtin_shufflevector(m8, m8, 4, 5, 6, 7);
    f32x4v m4 = __builtin_elementwise_max(c, d);
    return fmaxf(fmaxf(m4[0], m4[1]), fmaxf(m4[2], m4[3]));
}

static __device__ __forceinline__ float vsum16(const f32x16 v) {
    f32x8v a = __builtin_shufflevector(v, v, 0, 1, 2, 3, 4, 5, 6, 7);
    f32x8v b = __builtin_shufflevector(v, v, 8, 9, 10, 11, 12, 13, 14, 15);
    f32x8v s8 = a + b;
    f32x4v c = __builtin_shufflevector(s8, s8, 0, 1, 2, 3);
    f32x4v d = __builtin_shufflevector(s8, s8, 4, 5, 6, 7);
    f32x4v s4 = c + d;
    return (s4[0] + s4[1]) + (s4[2] + s4[3]);
}

// async global->LDS, 16B per lane; lds dest = uniform base + lane*16
static __device__ __forceinline__ void glds16(const void* g, void* l) {
    __builtin_amdgcn_global_load_lds(
        (const __attribute__((address_space(1))) unsigned int*)(uintptr_t)g,
        (__attribute__((address_space(3))) unsigned int*)(unsigned)(uintptr_t)l,
        16, 0, 0);
}

// ---------------- pairs kernel: replicate reference IoU-argmax bit-exactly ----------------
__global__ __launch_bounds__(256) void pairs_kernel(const float* __restrict__ centers,
                                                    int* __restrict__ p0,
                                                    int* __restrict__ p1) {
#pragma clang fp contract(off)
    __shared__ float x0s[S_], y0s[S_], x1s[S_], y1s[S_], areas[S_], l1s[S_];
    const int b = blockIdx.y;
    const int t = threadIdx.x;
    for (int idx = t; idx < S_; idx += 256) {
        const float4 c = *reinterpret_cast<const float4*>(centers + ((size_t)b * S_ + idx) * 4);
        const float cx = c.x, cy = c.y, hh = c.z, ww = c.w;  // order: cx, cy, h, w
        const float x0 = cx - 0.5f * ww;
        const float y0 = cy - 0.5f * hh;
        const float x1 = cx + 0.5f * ww;
        const float y1 = cy + 0.5f * hh;
        x0s[idx] = x0; y0s[idx] = y0; x1s[idx] = x1; y1s[idx] = y1;
        areas[idx] = (x1 - x0) * (y1 - y0);
        l1s[idx] = fabsf(x1 - x0) + fabsf(y1 - y0);
    }
    __syncthreads();
    const int i = blockIdx.x * 16 + (t >> 4);
    const int c16 = t & 15;
    const float x0i = x0s[i], y0i = y0s[i], x1i = x1s[i], y1i = y1s[i], ai = areas[i];
    float best = -1e38f; int arg = 0;
    const int j0 = c16 * 64;
    #pragma unroll 4
    for (int j = j0; j < j0 + 64; ++j) {
        // NOTE: replicates reference exactly, including maximum() used for BOTH mins and maxs
        float wx = fmaxf(x1i, x1s[j]) - fmaxf(x0i, x0s[j]);
        float wy = fmaxf(y1i, y1s[j]) - fmaxf(y0i, y0s[j]);
        wx = fmaxf(wx, 0.0f);
        wy = fmaxf(wy, 0.0f);
        const float inter = wx * wy;
        const float uni = (ai + areas[j]) - inter;
        float v = inter / uni;
        if (j == i) v = v - 1.0f;   // -eye AFTER the division, as in reference
        if (v > best) { best = v; arg = j; }   // first-occurrence-of-max within chunk
    }
    // merge 16 chunks: smaller j wins ties (first-occurrence argmax)
    #pragma unroll
    for (int m = 1; m <= 8; m <<= 1) {
        const float ob = __shfl_xor(best, m);
        const int oa = __shfl_xor(arg, m);
        if (ob > best || (ob == best && oa < arg)) { best = ob; arg = oa; }
    }
    if (c16 == 0) {
        const int partner = arg;
        const float l1i = l1s[i], l1p = l1s[partner];
        const int keep = (l1i >= l1p) ? 1 : 0;
        p0[b * S_ + i] = keep ? i : partner;
        p1[b * S_ + i] = keep ? partner : i;
    }
}

// ---------------- prep (fused): gathered K' bf16 (swizzled) + V^T bf16 (swizzled) ----------------
// Kg[bh][s][e ^ ((s&7)<<3)], Vt[bh][d][ (chunk ^ (d&7))*8 + e ] per 64-col tile
__global__ __launch_bounds__(256) void prep_kv(const float* __restrict__ k,
                                               const float* __restrict__ v,
                                               const int* __restrict__ p0,
                                               const int* __restrict__ p1,
                                               unsigned short* __restrict__ Kg,
                                               unsigned short* __restrict__ Vt) {
    __shared__ float tile[64][65];
    const int gid = blockIdx.x;                 // XCD-swizzled 1D grid: 1024 blocks
    const int stile = (gid >> 3) & 15;
    const int bh = ((gid >> 7) << 3) | (gid & 7);
    const int b = bh >> 3;
    const int s0 = stile * 64;
    const int t = threadIdx.x;
    // --- K gather part: one 16B store per lane per row-group ---
    {
        const float* kp = k + (size_t)bh * S_ * D_;
        const int* p0b = p0 + b * S_;
        const int* p1b = p1 + b * S_;
        const int chunk = t & 15;               // 16 chunks of 8 elems in the 128-wide row
        const int rsub = t >> 4;                // 16 rows per pass
        for (int it = 0; it < 4; ++it) {
            const int s = s0 + it * 16 + rsub;
            const int i0 = p0b[s], i1 = p1b[s];
            const float* src = (chunk < 8) ? (kp + (size_t)i0 * D_ + chunk * 8)
                                           : (kp + (size_t)i1 * D_ + (chunk - 8) * 8);
            const float4 f0 = *reinterpret_cast<const float4*>(src);
            const float4 f1 = *reinterpret_cast<const float4*>(src + 4);
            union { u32 u[4]; s16x8 v; } pk;
            pk.u[0] = cvtpk(f0.x, f0.y);
            pk.u[1] = cvtpk(f0.z, f0.w);
            pk.u[2] = cvtpk(f1.x, f1.y);
            pk.u[3] = cvtpk(f1.z, f1.w);
            unsigned short* row = Kg + ((size_t)bh * S_ + s) * 128;
            *reinterpret_cast<s16x8*>(row + (size_t)(chunk ^ (s & 7)) * 8) = pk.v;
        }
    }
    // --- V transpose part ---
    {
        const float* vp = v + ((size_t)bh * S_ + s0) * D_;
        const int row = t >> 2, cpart = (t & 3) * 16;
        for (int jj = 0; jj < 4; ++jj) {
            const float4 x = *reinterpret_cast<const float4*>(&vp[(size_t)row * D_ + cpart + jj * 4]);
            tile[row][cpart + jj * 4 + 0] = x.x;
            tile[row][cpart + jj * 4 + 1] = x.y;
            tile[row][cpart + jj * 4 + 2] = x.z;
            tile[row][cpart + jj * 4 + 3] = x.w;
        }
        __syncthreads();
        const int d = t >> 2;
        unsigned short* orow = Vt + ((size_t)bh * 64 + d) * S_ + s0;
        for (int cc = 0; cc < 2; ++cc) {
            const int chunk = (t & 3) * 2 + cc;       // 8-col chunk within this 64-col tile
            unsigned short hh[8];
            for (int e = 0; e < 8; ++e) hh[e] = f2bf(tile[chunk * 8 + e][d]);
            const int chunk2 = chunk ^ (d & 7);
            *reinterpret_cast<s16x8*>(&orow[chunk2 * 8]) = *reinterpret_cast<s16x8*>(hh);
        }
    }
}

// ---------------- fused flash attention: swapped QK^T (32x32 MFMA), in-reg softmax/P ----------------
// Triple-buffered LDS + split counted vmcnt (K before QK, V before PV), setprio, defer-max
__global__ __launch_bounds__(256, 2) void attn_kernel(const float* __restrict__ q,
                                                      const unsigned short* __restrict__ Kg,
                                                      const unsigned short* __restrict__ Vt,
                                                      const int* __restrict__ p0,
                                                      const int* __restrict__ p1,
                                                      float* __restrict__ out) {
    __shared__ __align__(16) unsigned short Ks[3][KT][128];  // 48KB, pre-swizzled
    __shared__ __align__(16) unsigned short Vs[3][D_][KT];   // 24KB, pre-swizzled [d][kk]

    const int tid = threadIdx.x;
    const int w = tid >> 6;          // wave 0..3
    const int lane = tid & 63;
    const int qc = lane & 31;        // q-row within wave tile / kcol within K-tile
    const int hi = lane >> 5;
    const int gid = blockIdx.x;      // XCD-swizzled 1D grid: 512 blocks
    const int qtile = (gid >> 3) & 7;
    const int bh = ((gid >> 6) << 3) | (gid & 7);
    const int b = bh >> 3;
    const int h = bh & 7;

    const float* qp = q + (size_t)bh * S_ * D_;
    const unsigned short* KgB = Kg + (size_t)bh * S_ * 128;
    const unsigned short* VtB = Vt + (size_t)bh * D_ * S_;

    // ---- gather this lane's Q' row slices into B-fragments (pre-scaled by CSCALE) ----
    s16x8 qf[8];
    {
        const int qr = qtile * QT + w * 32 + qc;
        const int i0 = p0[b * S_ + qr], i1 = p1[b * S_ + qr];
        #pragma unroll
        for (int p = 0; p < 8; ++p) {
            const int k0 = 16 * p + 8 * hi;
            const float* src = (p < 4) ? (qp + (size_t)i0 * D_ + k0)
                                       : (qp + (size_t)i1 * D_ + (k0 - 64));
            const float4 f0 = *reinterpret_cast<const float4*>(src);
            const float4 f1 = *reinterpret_cast<const float4*>(src + 4);
            union { u32 u[4]; s16x8 v; } pk;
            pk.u[0] = cvtpk(f0.x * CSCALE, f0.y * CSCALE);
            pk.u[1] = cvtpk(f0.z * CSCALE, f0.w * CSCALE);
            pk.u[2] = cvtpk(f1.x * CSCALE, f1.y * CSCALE);
            pk.u[3] = cvtpk(f1.z * CSCALE, f1.w * CSCALE);
            qf[p] = pk.v;
        }
    }

    // ---- staging helper: 6 x glds16 per wave per tile (4 K first, then 2 V) ----
    const int rK = lane >> 4;
    const size_t cK = (size_t)(lane & 15) * 8;
    const int rV = lane >> 3;
    const size_t cV8 = (size_t)(lane & 7) * 8;
    auto STAGE = [&](int kt, int bf) {
        const size_t kbase = (size_t)(kt * KT) * 128;
        #pragma unroll
        for (int qq = 0; qq < 4; ++qq)
            glds16(KgB + kbase + ((size_t)((w * 4 + qq) * 4 + rK)) * 128 + cK,
                   &Ks[bf][(w * 4 + qq) * 4][0]);
        #pragma unroll
        for (int qq = 0; qq < 2; ++qq)
            glds16(VtB + ((size_t)((w * 2 + qq) * 8 + rV)) * S_ + (size_t)(kt * KT) + cV8,
                   &Vs[bf][(w * 2 + qq) * 8][0]);
    };
    STAGE(0, 0);
    STAGE(1, 1);

    f32x16 oacc0 = {}, oacc1 = {};   // O^T accumulators: d-tiles 0/1 x qrow=qc
    float m_run = -1e30f, l_run = 0.0f;
    const int swz = qc & 7;
    int cur = 0, nxt2 = 2;

    for (int kt = 0; kt < NT; ++kt) {
        __builtin_amdgcn_s_barrier();   // all waves done reading buf[nxt2] (tile kt-1)
        if (kt + 2 < NT) STAGE(kt + 2, nxt2);

        // ---- wait K of tile kt only (V + younger staging stay in flight) ----
        if (kt + 2 < NT)      asm volatile("s_waitcnt vmcnt(14)" ::: "memory");
        else if (kt + 1 < NT) asm volatile("s_waitcnt vmcnt(8)" ::: "memory");
        else                  asm volatile("s_waitcnt vmcnt(2)" ::: "memory");

        const unsigned short(*KsC)[128] = Ks[cur];
        const unsigned short(*VsC)[KT] = Vs[cur];

        // ---- swapped QK^T: load all 16 K-fragments, then 16 MFMAs ----
        s16x8 kf0[8], kf1[8];
        #pragma unroll
        for (int p = 0; p < 8; ++p) {
            const int ch = (2 * p + hi) ^ swz;
            kf0[p] = *reinterpret_cast<const s16x8*>(&KsC[qc][ch * 8]);
            kf1[p] = *reinterpret_cast<const s16x8*>(&KsC[32 + qc][ch * 8]);
        }
        f32x16 st0 = {}, st1 = {};
        __builtin_amdgcn_s_setprio(1);
        #pragma unroll
        for (int p = 0; p < 8; ++p)
            st0 = __builtin_amdgcn_mfma_f32_32x32x16_bf16(kf0[p], qf[p], st0, 0, 0, 0);
        #pragma unroll
        for (int p = 0; p < 8; ++p)
            st1 = __builtin_amdgcn_mfma_f32_32x32x16_bf16(kf1[p], qf[p], st1, 0, 0, 0);
        __builtin_amdgcn_s_setprio(0);

        // ---- online softmax, split per 32-col block (st0 finish overlaps st1 MFMAs) ----
        {
            float mx = vmax16(st0);
            mx = fmaxf(mx, __shfl_xor(mx, 32));
            if (!__all(mx <= m_run + 8.0f)) {   // defer-max (T13)
                const float mn = fmaxf(m_run, mx);
                const float al = exp2f(m_run - mn);
                m_run = mn; l_run *= al;
                oacc0 *= al; oacc1 *= al;
            }
            #pragma unroll
            for (int i = 0; i < 16; ++i) st0[i] = exp2f(st0[i] - m_run);
            float ps = vsum16(st0);
            ps += __shfl_xor(ps, 32);
            l_run += ps;
        }
        {
            float mx = vmax16(st1);
            mx = fmaxf(mx, __shfl_xor(mx, 32));
            if (!__all(mx <= m_run + 8.0f)) {
                const float mn = fmaxf(m_run, mx);
                const float al = exp2f(m_run - mn);
                m_run = mn; l_run *= al;
                oacc0 *= al; oacc1 *= al;
            }
            #pragma unroll
            for (int i = 0; i < 16; ++i) st1[i] = exp2f(st1[i] - m_run);
            float ps = vsum16(st1);
            ps += __shfl_xor(ps, 32);
            l_run += ps;
        }

        // ---- pack P to bf16 pairs (in-register) ----
        u32 U0[8], U1[8];
        #pragma unroll
        for (int i = 0; i < 8; ++i) {
            U0[i] = cvtpk(st0[2 * i], st0[2 * i + 1]);
            U1[i] = cvtpk(st1[2 * i], st1[2 * i + 1]);
        }

        // ---- batched cross-half exchange: all 8 shfls up front ----
        u32 pfw[16];
        #pragma unroll
        for (int s = 0; s < 4; ++s) {
            const u32* Ut = (s < 2) ? U0 : U1;
            const int a = 4 * (s & 1);
            const u32 sendA = hi ? Ut[a] : Ut[a + 2];
            const u32 sendB = hi ? Ut[a + 1] : Ut[a + 3];
            const u32 recvA = __shfl_xor(sendA, 32);
            const u32 recvB = __shfl_xor(sendB, 32);
            pfw[4 * s + 0] = hi ? recvA : Ut[a];
            pfw[4 * s + 1] = hi ? recvB : Ut[a + 1];
            pfw[4 * s + 2] = hi ? Ut[a + 2] : recvA;
            pfw[4 * s + 3] = hi ? Ut[a + 3] : recvB;
        }

        // ---- wait V of tile kt, then PV cluster: 8 vf reads + 8 MFMAs ----
        if (kt + 2 < NT)      asm volatile("s_waitcnt vmcnt(12)" ::: "memory");
        else if (kt + 1 < NT) asm volatile("s_waitcnt vmcnt(6)" ::: "memory");
        else                  asm volatile("s_waitcnt vmcnt(0)" ::: "memory");

        s16x8 vf0[4], vf1[4];
        #pragma unroll
        for (int s = 0; s < 4; ++s) {
            const int ch = (2 * s + hi) ^ swz;
            vf0[s] = *reinterpret_cast<const s16x8*>(&VsC[qc][ch * 8]);
            vf1[s] = *reinterpret_cast<const s16x8*>(&VsC[32 + qc][ch * 8]);
        }
        __builtin_amdgcn_s_setprio(1);
        #pragma unroll
        for (int s = 0; s < 4; ++s) {
            union { u32 u[4]; s16x8 v; } pf;
            pf.u[0] = pfw[4 * s]; pf.u[1] = pfw[4 * s + 1];
            pf.u[2] = pfw[4 * s + 2]; pf.u[3] = pfw[4 * s + 3];
            oacc0 = __builtin_amdgcn_mfma_f32_32x32x16_bf16(vf0[s], pf.v, oacc0, 0, 0, 0);
            oacc1 = __builtin_amdgcn_mfma_f32_32x32x16_bf16(vf1[s], pf.v, oacc1, 0, 0, 0);
        }
        __builtin_amdgcn_s_setprio(0);

        cur = (cur + 1 == 3) ? 0 : cur + 1;
        nxt2 = (nxt2 + 1 == 3) ? 0 : nxt2 + 1;
    }

    // ---- epilogue: O^T[d][qrow=qc] -> out[b][qr][h*64+d], divide by l ----
    const float invl = 1.0f / l_run;
    const int qrg = qtile * QT + w * 32 + qc;
    float* orow = out + ((size_t)b * S_ + qrg) * (H_ * D_) + h * D_;
    #pragma unroll
    for (int rq = 0; rq < 4; ++rq) {
        const float4 v0 = { oacc0[4 * rq] * invl, oacc0[4 * rq + 1] * invl,
                            oacc0[4 * rq + 2] * invl, oacc0[4 * rq + 3] * invl };
        *reinterpret_cast<float4*>(orow + 8 * rq + 4 * hi) = v0;
        const float4 v1 = { oacc1[4 * rq] * invl, oacc1[4 * rq + 1] * invl,
                            oacc1[4 * rq + 2] * invl, oacc1[4 * rq + 3] * invl };
        *reinterpret_cast<float4*>(orow + 32 + 8 * rq + 4 * hi) = v1;
    }
}

extern "C" void kernel_launch(void* const* d_in, const int* in_sizes, int n_in,
                              void* d_out, int out_size, void* d_ws, size_t ws_size,
                              hipStream_t stream) {
    (void)in_sizes; (void)n_in; (void)out_size; (void)ws_size;
    const float* q = (const float*)d_in[0];
    const float* k = (const float*)d_in[1];
    const float* v = (const float*)d_in[2];
    const float* c = (const float*)d_in[3];
    float* out = (float*)d_out;
    int* p0 = (int*)d_ws;                                   // [B_, S_] = 32KB
    int* p1 = p0 + B_ * S_;                                 // 32KB
    unsigned short* Kg = (unsigned short*)((char*)d_ws + 65536);        // 16.8MB
    unsigned short* Vt = Kg + (size_t)B_ * H_ * S_ * 128;               // 8.4MB
    pairs_kernel<<<dim3(64, 8), 256, 0, stream>>>(c, p0, p1);
    prep_kv<<<dim3(1024), 256, 0, stream>>>(k, v, p0, p1, Kg, Vt);
    attn_kernel<<<dim3(512), 256, 0, stream>>>(q, Kg, Vt, p0, p1, out);
}